// Round 1
// baseline (233.543 us; speedup 1.0000x reference)
//
#include <hip/hip_runtime.h>

// FlowWarpConsistencyLoss: B=16, C=3, H=W=512, flow 2x128x128.
// out = (loss, loss) with loss = sum(charbonnier(prev_g - warp(next_g))) / count(valid)

constexpr int B  = 16;
constexpr int H  = 512;
constexpr int W  = 512;
constexpr int FH = 128;
constexpr int FW = 128;
constexpr int HW  = H * W;
constexpr int IMG = 3 * HW;    // elems per batch image
constexpr int FHW = FH * FW;
constexpr float EPS2 = 1e-6f;  // EPS^2, EPS = 0.001

__device__ __forceinline__ float gray(const float* __restrict__ img, int off) {
    return 0.299f * img[off] + 0.587f * img[HW + off] + 0.114f * img[2 * HW + off];
}

__global__ __launch_bounds__(256) void flow_loss_kernel(
    const float* __restrict__ prev, const float* __restrict__ nxt,
    const float* __restrict__ flow, double* __restrict__ loss_acc,
    unsigned int* __restrict__ cnt_acc)
{
    const int nquad = B * HW / 4;
    const float fr = (float)(127.0 / 511.0);   // (FH-1)/(H-1), matches jnp f32 scalar
    double lsum = 0.0;
    unsigned int lcnt = 0;

    for (int q = blockIdx.x * blockDim.x + threadIdx.x; q < nquad;
         q += gridDim.x * blockDim.x) {
        const int pix = q * 4;
        const int b   = pix / HW;
        const int rem = pix - b * HW;
        const int y   = rem >> 9;      // / 512
        const int x0  = rem & 511;

        const float* __restrict__ pb = prev + (long)b * IMG;
        const float* __restrict__ nb = nxt  + (long)b * IMG;
        const int row = y * W + x0;
        const float4 pr = *(const float4*)(pb + row);
        const float4 pg = *(const float4*)(pb + HW + row);
        const float4 pl = *(const float4*)(pb + 2 * HW + row);
        const float prevg[4] = {
            0.299f * pr.x + 0.587f * pg.x + 0.114f * pl.x,
            0.299f * pr.y + 0.587f * pg.y + 0.114f * pl.y,
            0.299f * pr.z + 0.587f * pg.z + 0.114f * pl.z,
            0.299f * pr.w + 0.587f * pg.w + 0.114f * pl.w };

        // flow row interp coords (shared across the 4 pixels: same y)
        const float* __restrict__ fu = flow + (long)b * 2 * FHW;
        const float* __restrict__ fv = fu + FHW;
        const float syf = (float)y * fr;
        const int   fy0 = (int)floorf(syf);
        const int   fy1 = min(fy0 + 1, FH - 1);
        const float wy  = syf - (float)fy0;

        #pragma unroll
        for (int i = 0; i < 4; ++i) {
            const int x = x0 + i;
            const float sxf = (float)x * fr;
            const int   fx0 = (int)floorf(sxf);
            const int   fx1 = min(fx0 + 1, FW - 1);
            const float wx  = sxf - (float)fx0;

            // bilinear on flow, row-first (matches reference op order), then *4 scale
            const float u00 = fu[fy0 * FW + fx0], u01 = fu[fy0 * FW + fx1];
            const float u10 = fu[fy1 * FW + fx0], u11 = fu[fy1 * FW + fx1];
            const float v00 = fv[fy0 * FW + fx0], v01 = fv[fy0 * FW + fx1];
            const float v10 = fv[fy1 * FW + fx0], v11 = fv[fy1 * FW + fx1];
            const float uh0 = u00 * (1.0f - wy) + u10 * wy;
            const float uh1 = u01 * (1.0f - wy) + u11 * wy;
            const float vh0 = v00 * (1.0f - wy) + v10 * wy;
            const float vh1 = v01 * (1.0f - wy) + v11 * wy;
            const float u = (uh0 * (1.0f - wx) + uh1 * wx) * 4.0f;
            const float v = (vh0 * (1.0f - wx) + vh1 * wx) * 4.0f;

            const float gx = (float)x + u;
            const float gy = (float)y + v;
            const bool valid = (gx >= 0.0f) & (gx <= (float)(W - 1)) &
                               (gy >= 0.0f) & (gy <= (float)(H - 1));
            if (!valid) continue;

            const float gxf = floorf(gx), gyf = floorf(gy);
            const float wwx = gx - gxf,  wwy = gy - gyf;
            const int ix0 = (int)gxf, iy0 = (int)gyf;
            const int ix1 = ix0 + 1,  iy1 = iy0 + 1;

            // per-corner validity + clamped gather (matches reference gather())
            float c00 = 0.0f, c01 = 0.0f, c10 = 0.0f, c11 = 0.0f;
            {
                const int xc0 = min(max(ix0, 0), W - 1), xc1 = min(max(ix1, 0), W - 1);
                const int yc0 = min(max(iy0, 0), H - 1), yc1 = min(max(iy1, 0), H - 1);
                const bool vx0 = (ix0 >= 0) & (ix0 <= W - 1);
                const bool vx1 = (ix1 >= 0) & (ix1 <= W - 1);
                const bool vy0 = (iy0 >= 0) & (iy0 <= H - 1);
                const bool vy1 = (iy1 >= 0) & (iy1 <= H - 1);
                if (vy0 & vx0) c00 = gray(nb, yc0 * W + xc0);
                if (vy0 & vx1) c01 = gray(nb, yc0 * W + xc1);
                if (vy1 & vx0) c10 = gray(nb, yc1 * W + xc0);
                if (vy1 & vx1) c11 = gray(nb, yc1 * W + xc1);
            }
            const float warped = c00 * (1.0f - wwx) * (1.0f - wwy)
                               + c01 * wwx * (1.0f - wwy)
                               + c10 * (1.0f - wwx) * wwy
                               + c11 * wwx * wwy;
            const float diff = prevg[i] - warped;
            lsum += (double)sqrtf(diff * diff + EPS2);
            lcnt += 1u;
        }
    }

    // wave64 reduce
    #pragma unroll
    for (int off = 32; off > 0; off >>= 1) {
        lsum += __shfl_down(lsum, off);
        lcnt += __shfl_down(lcnt, off);
    }
    __shared__ double s_sum[4];
    __shared__ unsigned int s_cnt[4];
    const int wid = threadIdx.x >> 6, lane = threadIdx.x & 63;
    if (lane == 0) { s_sum[wid] = lsum; s_cnt[wid] = lcnt; }
    __syncthreads();
    if (threadIdx.x == 0) {
        double t = s_sum[0] + s_sum[1] + s_sum[2] + s_sum[3];
        unsigned int c = s_cnt[0] + s_cnt[1] + s_cnt[2] + s_cnt[3];
        atomicAdd(loss_acc, t);
        atomicAdd(cnt_acc, c);
    }
}

__global__ void finalize_kernel(const double* __restrict__ loss_acc,
                                const unsigned int* __restrict__ cnt_acc,
                                float* __restrict__ out)
{
    double c = (double)(*cnt_acc);
    if (c < 1.0) c = 1.0;
    const float loss = (float)(*loss_acc / c);
    out[0] = loss;   // FLOW_WARP_WEIGHT * loss, weight = 1.0
    out[1] = loss;
}

extern "C" void kernel_launch(void* const* d_in, const int* in_sizes, int n_in,
                              void* d_out, int out_size, void* d_ws, size_t ws_size,
                              hipStream_t stream) {
    const float* prev = (const float*)d_in[0];
    const float* nxt  = (const float*)d_in[1];
    const float* flow = (const float*)d_in[2];
    float* out = (float*)d_out;

    double* loss_acc = (double*)d_ws;
    unsigned int* cnt_acc = (unsigned int*)((char*)d_ws + 8);

    hipMemsetAsync(d_ws, 0, 16, stream);   // ws is NOT re-poisoned between replays
    flow_loss_kernel<<<dim3(2048), dim3(256), 0, stream>>>(prev, nxt, flow,
                                                           loss_acc, cnt_acc);
    finalize_kernel<<<dim3(1), dim3(1), 0, stream>>>(loss_acc, cnt_acc, out);
}

// Round 2
// 126.283 us; speedup vs baseline: 1.8494x; 1.8494x over previous
//
#include <hip/hip_runtime.h>

// FlowWarpConsistencyLoss: B=16, C=3, H=W=512, flow 2x128x128.
// Two-pass: (1) grayscale pred_next -> d_ws buffer (16.8 MB),
//           (2) fused flow-upsample + bilinear warp gather + charbonnier reduce.
// Pass 2 uses XCD-chunked block swizzle so each XCD's gathers stay in its 4 MiB L2.

constexpr int B  = 16;
constexpr int H  = 512;
constexpr int W  = 512;
constexpr int FH = 128;
constexpr int FW = 128;
constexpr int HW  = H * W;          // 262144 = 2^18
constexpr int IMG = 3 * HW;
constexpr int FHW = FH * FW;
constexpr float EPS2 = 1e-6f;       // EPS^2, EPS = 0.001

// ---------------- pass 1: gray(next) ----------------
__global__ __launch_bounds__(256) void gray_next_kernel(
    const float* __restrict__ nxt, float* __restrict__ g)
{
    const int q   = blockIdx.x * 256 + threadIdx.x;   // quad index, 1,048,576 total
    const int b   = q >> 16;                          // 65536 quads per image
    const int off = (q & 65535) * 4;
    const float* __restrict__ nb = nxt + (long)b * IMG;
    const float4 r  = *(const float4*)(nb + off);
    const float4 gg = *(const float4*)(nb + HW + off);
    const float4 bl = *(const float4*)(nb + 2 * HW + off);
    float4 o;
    o.x = 0.299f * r.x + 0.587f * gg.x + 0.114f * bl.x;
    o.y = 0.299f * r.y + 0.587f * gg.y + 0.114f * bl.y;
    o.z = 0.299f * r.z + 0.587f * gg.z + 0.114f * bl.z;
    o.w = 0.299f * r.w + 0.587f * gg.w + 0.114f * bl.w;
    *(float4*)(g + (long)b * HW + off) = o;
}

// ---------------- pass 2: fused warp + loss ----------------
__global__ __launch_bounds__(256) void loss_kernel(
    const float* __restrict__ prev, const float* __restrict__ gnext,
    const float* __restrict__ flow, double* __restrict__ loss_acc,
    unsigned int* __restrict__ cnt_acc)
{
    // XCD-chunked swizzle: 4096 blocks, 8 XCDs x 512 contiguous blocks (= 2 images/XCD)
    const int bid = ((blockIdx.x & 7) << 9) | (blockIdx.x >> 3);
    const int q   = bid * 256 + threadIdx.x;
    const int pix = q * 4;
    const int b   = pix >> 18;
    const int rem = pix & (HW - 1);
    const int y   = rem >> 9;
    const int x0  = rem & 511;

    const float fr = (float)(127.0 / 511.0);
    const float* __restrict__ pb = prev  + (long)b * IMG;
    const float* __restrict__ gb = gnext + (long)b * HW;

    const int row = y * W + x0;
    const float4 pr = *(const float4*)(pb + row);
    const float4 pg = *(const float4*)(pb + HW + row);
    const float4 pl = *(const float4*)(pb + 2 * HW + row);
    const float prevg[4] = {
        0.299f * pr.x + 0.587f * pg.x + 0.114f * pl.x,
        0.299f * pr.y + 0.587f * pg.y + 0.114f * pl.y,
        0.299f * pr.z + 0.587f * pg.z + 0.114f * pl.z,
        0.299f * pr.w + 0.587f * pg.w + 0.114f * pl.w };

    const float* __restrict__ fu = flow + (long)b * 2 * FHW;
    const float* __restrict__ fv = fu + FHW;
    const float syf = (float)y * fr;
    const int   fy0 = (int)floorf(syf);
    const int   fy1 = min(fy0 + 1, FH - 1);
    const float wy  = syf - (float)fy0;

    double lsum = 0.0;
    unsigned int lcnt = 0;

    #pragma unroll
    for (int i = 0; i < 4; ++i) {
        const int x = x0 + i;
        const float sxf = (float)x * fr;
        const int   fx0 = (int)floorf(sxf);
        const int   fx1 = min(fx0 + 1, FW - 1);
        const float wx  = sxf - (float)fx0;

        const float u00 = fu[fy0 * FW + fx0], u01 = fu[fy0 * FW + fx1];
        const float u10 = fu[fy1 * FW + fx0], u11 = fu[fy1 * FW + fx1];
        const float v00 = fv[fy0 * FW + fx0], v01 = fv[fy0 * FW + fx1];
        const float v10 = fv[fy1 * FW + fx0], v11 = fv[fy1 * FW + fx1];
        const float uh0 = u00 * (1.0f - wy) + u10 * wy;
        const float uh1 = u01 * (1.0f - wy) + u11 * wy;
        const float vh0 = v00 * (1.0f - wy) + v10 * wy;
        const float vh1 = v01 * (1.0f - wy) + v11 * wy;
        const float u = (uh0 * (1.0f - wx) + uh1 * wx) * 4.0f;
        const float v = (vh0 * (1.0f - wx) + vh1 * wx) * 4.0f;

        const float gx = (float)x + u;
        const float gy = (float)y + v;
        const bool valid = (gx >= 0.0f) & (gx <= (float)(W - 1)) &
                           (gy >= 0.0f) & (gy <= (float)(H - 1));
        if (!valid) continue;

        const float gxf = floorf(gx), gyf = floorf(gy);
        const float wwx = gx - gxf,  wwy = gy - gyf;
        const int ix0 = (int)gxf, iy0 = (int)gyf;
        const int ix1 = ix0 + 1,  iy1 = iy0 + 1;

        const int xc0 = min(max(ix0, 0), W - 1), xc1 = min(max(ix1, 0), W - 1);
        const int yc0 = min(max(iy0, 0), H - 1), yc1 = min(max(iy1, 0), H - 1);
        const bool vx0 = (ix0 >= 0) & (ix0 <= W - 1);
        const bool vx1 = (ix1 >= 0) & (ix1 <= W - 1);
        const bool vy0 = (iy0 >= 0) & (iy0 <= H - 1);
        const bool vy1 = (iy1 >= 0) & (iy1 <= H - 1);
        float c00 = 0.0f, c01 = 0.0f, c10 = 0.0f, c11 = 0.0f;
        if (vy0 & vx0) c00 = gb[yc0 * W + xc0];
        if (vy0 & vx1) c01 = gb[yc0 * W + xc1];
        if (vy1 & vx0) c10 = gb[yc1 * W + xc0];
        if (vy1 & vx1) c11 = gb[yc1 * W + xc1];

        const float warped = c00 * (1.0f - wwx) * (1.0f - wwy)
                           + c01 * wwx * (1.0f - wwy)
                           + c10 * (1.0f - wwx) * wwy
                           + c11 * wwx * wwy;
        const float diff = prevg[i] - warped;
        lsum += (double)sqrtf(diff * diff + EPS2);
        lcnt += 1u;
    }

    // wave64 + block reduce
    #pragma unroll
    for (int off = 32; off > 0; off >>= 1) {
        lsum += __shfl_down(lsum, off);
        lcnt += __shfl_down(lcnt, off);
    }
    __shared__ double s_sum[4];
    __shared__ unsigned int s_cnt[4];
    const int wid = threadIdx.x >> 6, lane = threadIdx.x & 63;
    if (lane == 0) { s_sum[wid] = lsum; s_cnt[wid] = lcnt; }
    __syncthreads();
    if (threadIdx.x == 0) {
        double t = s_sum[0] + s_sum[1] + s_sum[2] + s_sum[3];
        unsigned int c = s_cnt[0] + s_cnt[1] + s_cnt[2] + s_cnt[3];
        atomicAdd(loss_acc, t);
        atomicAdd(cnt_acc, c);
    }
}

// ---------------- fallback single-pass (if ws too small) ----------------
__device__ __forceinline__ float gray3(const float* __restrict__ img, int off) {
    return 0.299f * img[off] + 0.587f * img[HW + off] + 0.114f * img[2 * HW + off];
}

__global__ __launch_bounds__(256) void flow_loss_mono_kernel(
    const float* __restrict__ prev, const float* __restrict__ nxt,
    const float* __restrict__ flow, double* __restrict__ loss_acc,
    unsigned int* __restrict__ cnt_acc)
{
    const int nquad = B * HW / 4;
    const float fr = (float)(127.0 / 511.0);
    double lsum = 0.0;
    unsigned int lcnt = 0;
    for (int q = blockIdx.x * blockDim.x + threadIdx.x; q < nquad;
         q += gridDim.x * blockDim.x) {
        const int pix = q * 4;
        const int b   = pix >> 18;
        const int rem = pix & (HW - 1);
        const int y   = rem >> 9;
        const int x0  = rem & 511;
        const float* __restrict__ pb = prev + (long)b * IMG;
        const float* __restrict__ nb = nxt  + (long)b * IMG;
        const int row = y * W + x0;
        const float4 pr = *(const float4*)(pb + row);
        const float4 pg = *(const float4*)(pb + HW + row);
        const float4 pl = *(const float4*)(pb + 2 * HW + row);
        const float prevg[4] = {
            0.299f * pr.x + 0.587f * pg.x + 0.114f * pl.x,
            0.299f * pr.y + 0.587f * pg.y + 0.114f * pl.y,
            0.299f * pr.z + 0.587f * pg.z + 0.114f * pl.z,
            0.299f * pr.w + 0.587f * pg.w + 0.114f * pl.w };
        const float* __restrict__ fu = flow + (long)b * 2 * FHW;
        const float* __restrict__ fv = fu + FHW;
        const float syf = (float)y * fr;
        const int   fy0 = (int)floorf(syf);
        const int   fy1 = min(fy0 + 1, FH - 1);
        const float wy  = syf - (float)fy0;
        #pragma unroll
        for (int i = 0; i < 4; ++i) {
            const int x = x0 + i;
            const float sxf = (float)x * fr;
            const int   fx0 = (int)floorf(sxf);
            const int   fx1 = min(fx0 + 1, FW - 1);
            const float wx  = sxf - (float)fx0;
            const float u00 = fu[fy0 * FW + fx0], u01 = fu[fy0 * FW + fx1];
            const float u10 = fu[fy1 * FW + fx0], u11 = fu[fy1 * FW + fx1];
            const float v00 = fv[fy0 * FW + fx0], v01 = fv[fy0 * FW + fx1];
            const float v10 = fv[fy1 * FW + fx0], v11 = fv[fy1 * FW + fx1];
            const float uh0 = u00 * (1.0f - wy) + u10 * wy;
            const float uh1 = u01 * (1.0f - wy) + u11 * wy;
            const float vh0 = v00 * (1.0f - wy) + v10 * wy;
            const float vh1 = v01 * (1.0f - wy) + v11 * wy;
            const float u = (uh0 * (1.0f - wx) + uh1 * wx) * 4.0f;
            const float v = (vh0 * (1.0f - wx) + vh1 * wx) * 4.0f;
            const float gx = (float)x + u;
            const float gy = (float)y + v;
            const bool valid = (gx >= 0.0f) & (gx <= (float)(W - 1)) &
                               (gy >= 0.0f) & (gy <= (float)(H - 1));
            if (!valid) continue;
            const float gxf = floorf(gx), gyf = floorf(gy);
            const float wwx = gx - gxf,  wwy = gy - gyf;
            const int ix0 = (int)gxf, iy0 = (int)gyf;
            const int ix1 = ix0 + 1,  iy1 = iy0 + 1;
            const int xc0 = min(max(ix0, 0), W - 1), xc1 = min(max(ix1, 0), W - 1);
            const int yc0 = min(max(iy0, 0), H - 1), yc1 = min(max(iy1, 0), H - 1);
            const bool vx0 = (ix0 >= 0) & (ix0 <= W - 1);
            const bool vx1 = (ix1 >= 0) & (ix1 <= W - 1);
            const bool vy0 = (iy0 >= 0) & (iy0 <= H - 1);
            const bool vy1 = (iy1 >= 0) & (iy1 <= H - 1);
            float c00 = 0.0f, c01 = 0.0f, c10 = 0.0f, c11 = 0.0f;
            if (vy0 & vx0) c00 = gray3(nb, yc0 * W + xc0);
            if (vy0 & vx1) c01 = gray3(nb, yc0 * W + xc1);
            if (vy1 & vx0) c10 = gray3(nb, yc1 * W + xc0);
            if (vy1 & vx1) c11 = gray3(nb, yc1 * W + xc1);
            const float warped = c00 * (1.0f - wwx) * (1.0f - wwy)
                               + c01 * wwx * (1.0f - wwy)
                               + c10 * (1.0f - wwx) * wwy
                               + c11 * wwx * wwy;
            const float diff = prevg[i] - warped;
            lsum += (double)sqrtf(diff * diff + EPS2);
            lcnt += 1u;
        }
    }
    #pragma unroll
    for (int off = 32; off > 0; off >>= 1) {
        lsum += __shfl_down(lsum, off);
        lcnt += __shfl_down(lcnt, off);
    }
    __shared__ double s_sum[4];
    __shared__ unsigned int s_cnt[4];
    const int wid = threadIdx.x >> 6, lane = threadIdx.x & 63;
    if (lane == 0) { s_sum[wid] = lsum; s_cnt[wid] = lcnt; }
    __syncthreads();
    if (threadIdx.x == 0) {
        double t = s_sum[0] + s_sum[1] + s_sum[2] + s_sum[3];
        unsigned int c = s_cnt[0] + s_cnt[1] + s_cnt[2] + s_cnt[3];
        atomicAdd(loss_acc, t);
        atomicAdd(cnt_acc, c);
    }
}

__global__ void finalize_kernel(const double* __restrict__ loss_acc,
                                const unsigned int* __restrict__ cnt_acc,
                                float* __restrict__ out)
{
    double c = (double)(*cnt_acc);
    if (c < 1.0) c = 1.0;
    const float loss = (float)(*loss_acc / c);
    out[0] = loss;
    out[1] = loss;
}

extern "C" void kernel_launch(void* const* d_in, const int* in_sizes, int n_in,
                              void* d_out, int out_size, void* d_ws, size_t ws_size,
                              hipStream_t stream) {
    const float* prev = (const float*)d_in[0];
    const float* nxt  = (const float*)d_in[1];
    const float* flow = (const float*)d_in[2];
    float* out = (float*)d_out;

    double* loss_acc = (double*)d_ws;
    unsigned int* cnt_acc = (unsigned int*)((char*)d_ws + 8);
    const size_t gray_bytes = (size_t)B * HW * sizeof(float);   // 16.8 MB

    hipMemsetAsync(d_ws, 0, 16, stream);   // ws is NOT re-poisoned between replays

    if (ws_size >= 256 + gray_bytes) {
        float* gbuf = (float*)((char*)d_ws + 256);
        gray_next_kernel<<<dim3(B * HW / 4 / 256), dim3(256), 0, stream>>>(nxt, gbuf);
        loss_kernel<<<dim3(B * HW / 4 / 256), dim3(256), 0, stream>>>(
            prev, gbuf, flow, loss_acc, cnt_acc);
    } else {
        flow_loss_mono_kernel<<<dim3(2048), dim3(256), 0, stream>>>(
            prev, nxt, flow, loss_acc, cnt_acc);
    }
    finalize_kernel<<<dim3(1), dim3(1), 0, stream>>>(loss_acc, cnt_acc, out);
}

// Round 3
// 123.810 us; speedup vs baseline: 1.8863x; 1.0200x over previous
//
#include <hip/hip_runtime.h>

// FlowWarpConsistencyLoss: B=16, C=3, H=W=512, flow 2x128x128.
// Pass 1: grayscale pred_next -> d_ws (16.8 MB).
// Pass 2: branchless fused flow-upsample + warp-gather + charbonnier reduce.
//   Thread = 1 column x 4 rows -> flow weights shared across the thread's pixels
//   (12 flow loads instead of 32), wave footprint 64x * 4y for gather locality,
//   all loads unconditional (clamped) so they batch into few vmcnt epochs.

constexpr int B  = 16;
constexpr int H  = 512;
constexpr int W  = 512;
constexpr int FH = 128;
constexpr int FW = 128;
constexpr int HW  = H * W;          // 262144 = 2^18
constexpr int IMG = 3 * HW;
constexpr int FHW = FH * FW;
constexpr float EPS = 0.001f;

// ---------------- pass 1: gray(next) ----------------
__global__ __launch_bounds__(256) void gray_next_kernel(
    const float* __restrict__ nxt, float* __restrict__ g)
{
    const int q   = blockIdx.x * 256 + threadIdx.x;   // quad index
    const int b   = q >> 16;
    const int off = (q & 65535) * 4;
    const float* __restrict__ nb = nxt + (long)b * IMG;
    const float4 r  = *(const float4*)(nb + off);
    const float4 gg = *(const float4*)(nb + HW + off);
    const float4 bl = *(const float4*)(nb + 2 * HW + off);
    float4 o;
    o.x = 0.299f * r.x + 0.587f * gg.x + 0.114f * bl.x;
    o.y = 0.299f * r.y + 0.587f * gg.y + 0.114f * bl.y;
    o.z = 0.299f * r.z + 0.587f * gg.z + 0.114f * bl.z;
    o.w = 0.299f * r.w + 0.587f * gg.w + 0.114f * bl.w;
    *(float4*)(g + (long)b * HW + off) = o;
}

// ---------------- pass 2: fused warp + loss ----------------
__global__ __launch_bounds__(256) void loss_kernel(
    const float* __restrict__ prev, const float* __restrict__ gnext,
    const float* __restrict__ flow, double* __restrict__ loss_acc,
    unsigned int* __restrict__ cnt_acc)
{
    // 4096 blocks; XCD-chunked: 8 XCDs x 512 contiguous (= 2 images each).
    const int bid = ((blockIdx.x & 7) << 9) | (blockIdx.x >> 3);
    const int b   = bid >> 8;              // 256 blocks per image
    const int rr_ = bid & 255;
    const int x   = ((rr_ & 1) << 8) | threadIdx.x;   // 0..511
    const int y0  = (rr_ >> 1) << 2;                  // 4-row stripe

    const float fr = (float)(127.0 / 511.0);

    // ---- flow corner loads: shared fx0/fx1/wx across this thread's 4 pixels ----
    const float* __restrict__ fu = flow + (long)b * 2 * FHW;
    const float* __restrict__ fv = fu + FHW;
    const float sxf = (float)x * fr;
    const int   fx0 = (int)sxf;                 // x>=0: trunc == floor
    const int   fx1 = min(fx0 + 1, FW - 1);
    const float wx  = sxf - (float)fx0;
    const int   fb  = (int)((float)y0 * fr);    // base flow row

    float uu[3][2], vv[3][2];
    #pragma unroll
    for (int k = 0; k < 3; ++k) {
        const int rw = min(fb + k, FH - 1) * FW;
        uu[k][0] = fu[rw + fx0];  uu[k][1] = fu[rw + fx1];
        vv[k][0] = fv[rw + fx0];  vv[k][1] = fv[rw + fx1];
    }

    // ---- prev grayscale (coalesced scalar loads, 12 total) ----
    const float* __restrict__ pb = prev + (long)b * IMG + (y0 * W + x);
    float pg[4];
    #pragma unroll
    for (int j = 0; j < 4; ++j) {
        const float rc = pb[j * W];
        const float gc = pb[HW + j * W];
        const float bc = pb[2 * HW + j * W];
        pg[j] = 0.299f * rc + 0.587f * gc + 0.114f * bc;
    }

    // ---- per-pixel flow interp -> gather addresses (branchless) ----
    float wwx[4], wwy[4], vmask[4];
    int a00[4], a01[4], a10[4], a11[4];
    #pragma unroll
    for (int j = 0; j < 4; ++j) {
        const float syf = (float)(y0 + j) * fr;
        const int   fy0 = (int)syf;
        const int   k   = fy0 - fb;            // 0 or 1
        const float wy  = syf - (float)fy0;

        const float u0a = k ? uu[1][0] : uu[0][0];
        const float u0b = k ? uu[2][0] : uu[1][0];
        const float u1a = k ? uu[1][1] : uu[0][1];
        const float u1b = k ? uu[2][1] : uu[1][1];
        const float v0a = k ? vv[1][0] : vv[0][0];
        const float v0b = k ? vv[2][0] : vv[1][0];
        const float v1a = k ? vv[1][1] : vv[0][1];
        const float v1b = k ? vv[2][1] : vv[1][1];

        // row-lerp then col-lerp (reference op order), then *4 scale
        const float uc0 = u0a * (1.0f - wy) + u0b * wy;
        const float uc1 = u1a * (1.0f - wy) + u1b * wy;
        const float vc0 = v0a * (1.0f - wy) + v0b * wy;
        const float vc1 = v1a * (1.0f - wy) + v1b * wy;
        const float u = (uc0 * (1.0f - wx) + uc1 * wx) * 4.0f;
        const float v = (vc0 * (1.0f - wx) + vc1 * wx) * 4.0f;

        const float gx = (float)x + u;
        const float gy = (float)(y0 + j) + v;
        vmask[j] = ((gx >= 0.0f) & (gx <= (float)(W - 1)) &
                    (gy >= 0.0f) & (gy <= (float)(H - 1))) ? 1.0f : 0.0f;

        const float gxf = floorf(gx), gyf = floorf(gy);
        wwx[j] = gx - gxf;
        wwy[j] = gy - gyf;
        const int ix0 = (int)gxf, iy0 = (int)gyf;
        const int xc0 = min(max(ix0, 0), W - 1);
        const int xc1 = min(max(ix0 + 1, 0), W - 1);
        const int yc0 = min(max(iy0, 0), H - 1);
        const int yc1 = min(max(iy0 + 1, 0), H - 1);
        a00[j] = yc0 * W + xc0;  a01[j] = yc0 * W + xc1;
        a10[j] = yc1 * W + xc0;  a11[j] = yc1 * W + xc1;
    }

    // ---- gathers: unconditional, all 16 batch into one epoch ----
    const float* __restrict__ gb = gnext + (long)b * HW;
    float c00[4], c01[4], c10[4], c11[4];
    #pragma unroll
    for (int j = 0; j < 4; ++j) {
        c00[j] = gb[a00[j]];  c01[j] = gb[a01[j]];
        c10[j] = gb[a10[j]];  c11[j] = gb[a11[j]];
    }

    // ---- combine ----
    double lsum = 0.0;
    unsigned int lcnt = 0;
    #pragma unroll
    for (int j = 0; j < 4; ++j) {
        const float warped = c00[j] * (1.0f - wwx[j]) * (1.0f - wwy[j])
                           + c01[j] * wwx[j] * (1.0f - wwy[j])
                           + c10[j] * (1.0f - wwx[j]) * wwy[j]
                           + c11[j] * wwx[j] * wwy[j];
        const float diff = pg[j] - warped;
        const float l = sqrtf(diff * diff + EPS * EPS);
        lsum += (double)(l * vmask[j]);
        lcnt += (unsigned int)vmask[j];
    }

    // ---- wave64 + block reduce ----
    #pragma unroll
    for (int off = 32; off > 0; off >>= 1) {
        lsum += __shfl_down(lsum, off);
        lcnt += __shfl_down(lcnt, off);
    }
    __shared__ double s_sum[4];
    __shared__ unsigned int s_cnt[4];
    const int wid = threadIdx.x >> 6, lane = threadIdx.x & 63;
    if (lane == 0) { s_sum[wid] = lsum; s_cnt[wid] = lcnt; }
    __syncthreads();
    if (threadIdx.x == 0) {
        double t = s_sum[0] + s_sum[1] + s_sum[2] + s_sum[3];
        unsigned int c = s_cnt[0] + s_cnt[1] + s_cnt[2] + s_cnt[3];
        atomicAdd(loss_acc, t);
        atomicAdd(cnt_acc, c);
    }
}

// ---------------- fallback single-pass (if ws too small) ----------------
__device__ __forceinline__ float gray3(const float* __restrict__ img, int off) {
    return 0.299f * img[off] + 0.587f * img[HW + off] + 0.114f * img[2 * HW + off];
}

__global__ __launch_bounds__(256) void flow_loss_mono_kernel(
    const float* __restrict__ prev, const float* __restrict__ nxt,
    const float* __restrict__ flow, double* __restrict__ loss_acc,
    unsigned int* __restrict__ cnt_acc)
{
    const int nquad = B * HW / 4;
    const float fr = (float)(127.0 / 511.0);
    double lsum = 0.0;
    unsigned int lcnt = 0;
    for (int q = blockIdx.x * blockDim.x + threadIdx.x; q < nquad;
         q += gridDim.x * blockDim.x) {
        const int pix = q * 4;
        const int b   = pix >> 18;
        const int rem = pix & (HW - 1);
        const int y   = rem >> 9;
        const int x0  = rem & 511;
        const float* __restrict__ pb = prev + (long)b * IMG;
        const float* __restrict__ nb = nxt  + (long)b * IMG;
        const float* __restrict__ fu = flow + (long)b * 2 * FHW;
        const float* __restrict__ fv = fu + FHW;
        const float syf = (float)y * fr;
        const int   fy0 = (int)syf;
        const int   fy1 = min(fy0 + 1, FH - 1);
        const float wy  = syf - (float)fy0;
        #pragma unroll
        for (int i = 0; i < 4; ++i) {
            const int x = x0 + i;
            const float sxf = (float)x * fr;
            const int   fx0 = (int)sxf;
            const int   fx1 = min(fx0 + 1, FW - 1);
            const float wx  = sxf - (float)fx0;
            const float uc0 = fu[fy0 * FW + fx0] * (1.0f - wy) + fu[fy1 * FW + fx0] * wy;
            const float uc1 = fu[fy0 * FW + fx1] * (1.0f - wy) + fu[fy1 * FW + fx1] * wy;
            const float vc0 = fv[fy0 * FW + fx0] * (1.0f - wy) + fv[fy1 * FW + fx0] * wy;
            const float vc1 = fv[fy0 * FW + fx1] * (1.0f - wy) + fv[fy1 * FW + fx1] * wy;
            const float u = (uc0 * (1.0f - wx) + uc1 * wx) * 4.0f;
            const float v = (vc0 * (1.0f - wx) + vc1 * wx) * 4.0f;
            const float gx = (float)x + u;
            const float gy = (float)y + v;
            const float vm = ((gx >= 0.0f) & (gx <= (float)(W - 1)) &
                              (gy >= 0.0f) & (gy <= (float)(H - 1))) ? 1.0f : 0.0f;
            const float gxf = floorf(gx), gyf = floorf(gy);
            const float wwx = gx - gxf, wwy = gy - gyf;
            const int ix0 = (int)gxf, iy0 = (int)gyf;
            const int xc0 = min(max(ix0, 0), W - 1), xc1 = min(max(ix0 + 1, 0), W - 1);
            const int yc0 = min(max(iy0, 0), H - 1), yc1 = min(max(iy0 + 1, 0), H - 1);
            const float c00 = gray3(nb, yc0 * W + xc0);
            const float c01 = gray3(nb, yc0 * W + xc1);
            const float c10 = gray3(nb, yc1 * W + xc0);
            const float c11 = gray3(nb, yc1 * W + xc1);
            const float warped = c00 * (1.0f - wwx) * (1.0f - wwy)
                               + c01 * wwx * (1.0f - wwy)
                               + c10 * (1.0f - wwx) * wwy
                               + c11 * wwx * wwy;
            const float pgv = gray3(pb, y * W + x);
            const float diff = pgv - warped;
            const float l = sqrtf(diff * diff + EPS * EPS);
            lsum += (double)(l * vm);
            lcnt += (unsigned int)vm;
        }
    }
    #pragma unroll
    for (int off = 32; off > 0; off >>= 1) {
        lsum += __shfl_down(lsum, off);
        lcnt += __shfl_down(lcnt, off);
    }
    __shared__ double s_sum[4];
    __shared__ unsigned int s_cnt[4];
    const int wid = threadIdx.x >> 6, lane = threadIdx.x & 63;
    if (lane == 0) { s_sum[wid] = lsum; s_cnt[wid] = lcnt; }
    __syncthreads();
    if (threadIdx.x == 0) {
        double t = s_sum[0] + s_sum[1] + s_sum[2] + s_sum[3];
        unsigned int c = s_cnt[0] + s_cnt[1] + s_cnt[2] + s_cnt[3];
        atomicAdd(loss_acc, t);
        atomicAdd(cnt_acc, c);
    }
}

__global__ void finalize_kernel(const double* __restrict__ loss_acc,
                                const unsigned int* __restrict__ cnt_acc,
                                float* __restrict__ out)
{
    double c = (double)(*cnt_acc);
    if (c < 1.0) c = 1.0;
    const float loss = (float)(*loss_acc / c);
    out[0] = loss;
    out[1] = loss;
}

extern "C" void kernel_launch(void* const* d_in, const int* in_sizes, int n_in,
                              void* d_out, int out_size, void* d_ws, size_t ws_size,
                              hipStream_t stream) {
    const float* prev = (const float*)d_in[0];
    const float* nxt  = (const float*)d_in[1];
    const float* flow = (const float*)d_in[2];
    float* out = (float*)d_out;

    double* loss_acc = (double*)d_ws;
    unsigned int* cnt_acc = (unsigned int*)((char*)d_ws + 8);
    const size_t gray_bytes = (size_t)B * HW * sizeof(float);   // 16.8 MB

    hipMemsetAsync(d_ws, 0, 16, stream);   // ws is NOT re-poisoned between replays

    if (ws_size >= 256 + gray_bytes) {
        float* gbuf = (float*)((char*)d_ws + 256);
        gray_next_kernel<<<dim3(B * HW / 4 / 256), dim3(256), 0, stream>>>(nxt, gbuf);
        loss_kernel<<<dim3(4096), dim3(256), 0, stream>>>(
            prev, gbuf, flow, loss_acc, cnt_acc);
    } else {
        flow_loss_mono_kernel<<<dim3(2048), dim3(256), 0, stream>>>(
            prev, nxt, flow, loss_acc, cnt_acc);
    }
    finalize_kernel<<<dim3(1), dim3(1), 0, stream>>>(loss_acc, cnt_acc, out);
}